// Round 2
// baseline (295.136 us; speedup 1.0000x reference)
//
#include <hip/hip_runtime.h>
#include <hip/hip_bf16.h>

// EnhancedDiffusionLayer: 10 ADI steps, B=16 C=8 S=128.
// Tridiagonal systems are extremely diagonally dominant (off-diag/diag
// <= 0.005) -> Thomas replaced by x0=d/b + 3 Jacobi sweeps (rel err ~1e-8).
// Input dtype (f32 vs bf16) is detected at runtime from the bit patterns of
// u: a true-f32 N(0,1) buffer has ~all values finite in (1e-9,1e9); a bf16
// buffer reinterpreted as f32 has ~none (exponent bits come from mantissa).
// Output dtype follows the detected input dtype.

constexpr int BN = 16;
constexpr int CN = 8;
constexpr int SN = 128;
constexpr int SS = SN * SN;          // 16384
constexpr float DTC  = 0.001f;
constexpr float EPSC = 1e-6f;
constexpr int NSTEPS = 10;

__device__ __forceinline__ float sigm(float x) {
    return 1.0f / (1.0f + __expf(-x));
}
__device__ __forceinline__ float clampA(float x) {
    return fminf(fmaxf(x, EPSC), 5.0f);
}
__device__ __forceinline__ float cvt(float v) { return v; }
__device__ __forceinline__ float cvt(__hip_bfloat16 v) { return __bfloat162float(v); }
template<typename T>
__device__ __forceinline__ float ld(const void* p, int i) {
    return cvt(((const T*)p)[i]);
}
__device__ __forceinline__ void stv(float* p, int i, float v) { p[i] = v; }
__device__ __forceinline__ void stv(__hip_bfloat16* p, int i, float v) {
    p[i] = __float2bfloat16(v);
}

// ---------------- dtype detection ----------------------------------------
__global__ __launch_bounds__(256) void detect_kernel(const void* u, int* flag) {
    __shared__ int cnt;
    if (threadIdx.x == 0) cnt = 0;
    __syncthreads();
    float v = ((const float*)u)[threadIdx.x];
    float a = fabsf(v);
    int ok = (v == v) && (a < 1e9f) && (v == 0.0f || a > 1e-9f);
    atomicAdd(&cnt, ok);
    __syncthreads();
    if (threadIdx.x == 0) *flag = (cnt >= 128) ? 1 : 0;   // 1 == float32
}

// ---------------- Kernel A: coupling + cf + first x half-solve (step 0) ---
template<typename T>
__device__ __forceinline__ void ka_body(
    const void* u, const void* ab, const void* atc, const void* atq,
    const void* coup, const void* bwt,
    float* UF, float* CFUC, float t0,
    float (&K)[CN][CN], float (&xs)[CN][SN + 2])
{
    const int i = threadIdx.x;
    if (i < CN * CN) K[i / CN][i % CN] = ld<T>(coup, i);
    if (i < CN) { xs[i][0] = 0.0f; xs[i][SN + 1] = 0.0f; }
    const int b = blockIdx.x / SN;
    const int h = blockIdx.x % SN;
    const float wL = sigm(ld<T>(bwt, 3));
    const float wR = sigm(ld<T>(bwt, 1));
    const int baseU = b * CN * SS + h * SN + i;
    const int baseP = h * SN + i;

    float uch[CN];
    float ssum = 0.0f;
    #pragma unroll
    for (int c = 0; c < CN; ++c) {
        uch[c] = ld<T>(u, baseU + c * SS);
        ssum += sigm(uch[c]);
    }
    const float cfu = 1.0f + 0.1f * (ssum * 0.125f - 0.5f);
    __syncthreads();  // K + halo ready
    float uc[CN];
    float ssum2 = 0.0f;
    #pragma unroll
    for (int c = 0; c < CN; ++c) {
        float acc = 0.0f;
        #pragma unroll
        for (int d = 0; d < CN; ++d) acc += K[c][d] * uch[d];
        uc[c] = acc;
        ssum2 += sigm(acc);
    }
    CFUC[(b * SN + h) * SN + i] = 1.0f + 0.1f * (ssum2 * 0.125f - 0.5f);

    const float bfac = (i == 0) ? wL : (i == SN - 1) ? wR : 2.0f;
    float coeff[CN], invb[CN], x[CN];
    #pragma unroll
    for (int c = 0; c < CN; ++c) {
        const int p = baseP + c * SS;
        float al = ld<T>(ab, p) + ld<T>(atc, p) * t0 + ld<T>(atq, p) * (t0 * t0);
        al = clampA(al * cfu);
        const float cf_ = al * (DTC * 0.5f);
        coeff[c] = cf_;
        invb[c] = 1.0f / (1.0f + cf_ * bfac + EPSC);
        x[c] = uc[c] * invb[c];
    }
    #pragma unroll
    for (int it = 0; it < 3; ++it) {
        #pragma unroll
        for (int c = 0; c < CN; ++c) xs[c][i + 1] = x[c];
        __syncthreads();
        #pragma unroll
        for (int c = 0; c < CN; ++c)
            x[c] = (uc[c] + coeff[c] * (xs[c][i] + xs[c][i + 2])) * invb[c];
        __syncthreads();
    }
    #pragma unroll
    for (int c = 0; c < CN; ++c) UF[baseU + c * SS] = x[c];
}

__global__ __launch_bounds__(128) void ka_kernel(
    const void* u, const void* ab, const void* atc, const void* atq,
    const void* coup, const void* bwt,
    float* __restrict__ UF, float* __restrict__ CFUC, float t0,
    const int* __restrict__ flag)
{
    __shared__ float K[CN][CN];
    __shared__ float xs[CN][SN + 2];
    if (*flag)
        ka_body<float>(u, ab, atc, atq, coup, bwt, UF, CFUC, t0, K, xs);
    else
        ka_body<__hip_bfloat16>(u, ab, atc, atq, coup, bwt, UF, CFUC, t0, K, xs);
}

// ---------------- Kernel B: y full-step solve ----------------------------
template<typename T>
__device__ __forceinline__ void kb_body(
    const void* bb, const void* btc, const void* btq, const void* bwt,
    float* UF, const float* CFUC, float t2, float (&xs)[SN][33])
{
    const int tid = threadIdx.x;
    const int tx = tid & 31;
    const int ty = tid >> 5;
    const int wblk = blockIdx.x & 3;
    const int bc = blockIdx.x >> 2;
    const int c = bc & 7;
    const int b = bc >> 3;
    const int w = wblk * 32 + tx;
    const float wT = sigm(ld<T>(bwt, 0));
    const float wB = sigm(ld<T>(bwt, 2));
    const float t2sq = t2 * t2;

    float dd[16], coeff[16], invb[16], x[16];
    #pragma unroll
    for (int j = 0; j < 16; ++j) {
        const int h = ty + j * 8;
        dd[j] = UF[((b * CN + c) * SN + h) * SN + w];
        const int p = (c * SN + h) * SN + w;
        float be = ld<T>(bb, p) + ld<T>(btc, p) * t2 + ld<T>(btq, p) * t2sq;
        be = clampA(be * CFUC[(b * SN + h) * SN + w]);
        const float cf_ = be * DTC;   // full step, DY=1
        coeff[j] = cf_;
        const float bfac = (h == 0) ? wT : (h == SN - 1) ? wB : 2.0f;
        invb[j] = 1.0f / (1.0f + cf_ * bfac + EPSC);
        x[j] = dd[j] * invb[j];
    }
    #pragma unroll
    for (int it = 0; it < 3; ++it) {
        #pragma unroll
        for (int j = 0; j < 16; ++j) xs[ty + j * 8][tx] = x[j];
        __syncthreads();
        #pragma unroll
        for (int j = 0; j < 16; ++j) {
            const int h = ty + j * 8;
            const float xl = (h == 0) ? 0.0f : xs[h - 1][tx];
            const float xr = (h == SN - 1) ? 0.0f : xs[h + 1][tx];
            x[j] = (dd[j] + coeff[j] * (xl + xr)) * invb[j];
        }
        __syncthreads();
    }
    #pragma unroll
    for (int j = 0; j < 16; ++j) {
        const int h = ty + j * 8;
        UF[((b * CN + c) * SN + h) * SN + w] = x[j];
    }
}

__global__ __launch_bounds__(256) void kb_kernel(
    const void* bb, const void* btc, const void* btq, const void* bwt,
    float* __restrict__ UF, const float* __restrict__ CFUC, float t2,
    const int* __restrict__ flag)
{
    __shared__ float xs[SN][33];
    if (*flag)
        kb_body<float>(bb, btc, btq, bwt, UF, CFUC, t2, xs);
    else
        kb_body<__hip_bfloat16>(bb, btc, btq, bwt, UF, CFUC, t2, xs);
}

// ------- Kernel C: final x half-solve fused with next step's
//         coupling + cf + first x half-solve (same t value) --------------
template<typename T>
__device__ __forceinline__ void kc_body(
    const void* ab, const void* atc, const void* atq,
    const void* coup, const void* bwt,
    float* UF, float* CFUC, void* out, float t3, int last,
    float (&K)[CN][CN], float (&xs)[CN][SN + 2])
{
    const int i = threadIdx.x;
    if (i < CN * CN) K[i / CN][i % CN] = ld<T>(coup, i);
    if (i < CN) { xs[i][0] = 0.0f; xs[i][SN + 1] = 0.0f; }
    const int b = blockIdx.x / SN;
    const int h = blockIdx.x % SN;
    const float wL = sigm(ld<T>(bwt, 3));
    const float wR = sigm(ld<T>(bwt, 1));
    const int baseU = b * CN * SS + h * SN + i;
    const int baseP = h * SN + i;
    const float cfuc = CFUC[(b * SN + h) * SN + i];
    const float bfac = (i == 0) ? wL : (i == SN - 1) ? wR : 2.0f;

    float alin[CN], dd[CN], coeff[CN], invb[CN], x[CN];
    #pragma unroll
    for (int c = 0; c < CN; ++c) {
        const int p = baseP + c * SS;
        alin[c] = ld<T>(ab, p) + ld<T>(atc, p) * t3 + ld<T>(atq, p) * (t3 * t3);
        dd[c] = UF[baseU + c * SS];
        const float cf_ = clampA(alin[c] * cfuc) * (DTC * 0.5f);
        coeff[c] = cf_;
        invb[c] = 1.0f / (1.0f + cf_ * bfac + EPSC);
        x[c] = dd[c] * invb[c];
    }
    __syncthreads();  // K + halo ready
    #pragma unroll
    for (int it = 0; it < 3; ++it) {
        #pragma unroll
        for (int c = 0; c < CN; ++c) xs[c][i + 1] = x[c];
        __syncthreads();
        #pragma unroll
        for (int c = 0; c < CN; ++c)
            x[c] = (dd[c] + coeff[c] * (xs[c][i] + xs[c][i + 2])) * invb[c];
        __syncthreads();
    }
    if (last) {
        #pragma unroll
        for (int c = 0; c < CN; ++c)
            stv((T*)out, baseU + c * SS, x[c]);
        return;
    }
    // next step begins on x[] (the new u for this (b,h,:) row, all channels)
    float ssum = 0.0f;
    #pragma unroll
    for (int c = 0; c < CN; ++c) ssum += sigm(x[c]);
    const float cfu = 1.0f + 0.1f * (ssum * 0.125f - 0.5f);
    float uc[CN];
    float ssum2 = 0.0f;
    #pragma unroll
    for (int c = 0; c < CN; ++c) {
        float acc = 0.0f;
        #pragma unroll
        for (int d = 0; d < CN; ++d) acc += K[c][d] * x[d];
        uc[c] = acc;
        ssum2 += sigm(acc);
    }
    CFUC[(b * SN + h) * SN + i] = 1.0f + 0.1f * (ssum2 * 0.125f - 0.5f);
    float x2[CN];
    #pragma unroll
    for (int c = 0; c < CN; ++c) {
        const float cf_ = clampA(alin[c] * cfu) * (DTC * 0.5f);  // next t0 == t3
        coeff[c] = cf_;
        invb[c] = 1.0f / (1.0f + cf_ * bfac + EPSC);
        x2[c] = uc[c] * invb[c];
    }
    #pragma unroll
    for (int it = 0; it < 3; ++it) {
        #pragma unroll
        for (int c = 0; c < CN; ++c) xs[c][i + 1] = x2[c];
        __syncthreads();
        #pragma unroll
        for (int c = 0; c < CN; ++c)
            x2[c] = (uc[c] + coeff[c] * (xs[c][i] + xs[c][i + 2])) * invb[c];
        __syncthreads();
    }
    #pragma unroll
    for (int c = 0; c < CN; ++c) UF[baseU + c * SS] = x2[c];
}

__global__ __launch_bounds__(128) void kc_kernel(
    const void* ab, const void* atc, const void* atq,
    const void* coup, const void* bwt,
    float* __restrict__ UF, float* __restrict__ CFUC, void* out,
    float t3, int last, const int* __restrict__ flag)
{
    __shared__ float K[CN][CN];
    __shared__ float xs[CN][SN + 2];
    if (*flag)
        kc_body<float>(ab, atc, atq, coup, bwt, UF, CFUC, out, t3, last, K, xs);
    else
        kc_body<__hip_bfloat16>(ab, atc, atq, coup, bwt, UF, CFUC, out, t3, last, K, xs);
}

extern "C" void kernel_launch(void* const* d_in, const int* in_sizes, int n_in,
                              void* d_out, int out_size, void* d_ws, size_t ws_size,
                              hipStream_t stream)
{
    (void)in_sizes; (void)n_in; (void)out_size; (void)ws_size;
    const void* u    = d_in[0];
    const void* ab   = d_in[1];
    const void* bb   = d_in[2];
    const void* atc  = d_in[3];
    const void* btc  = d_in[4];
    const void* atq  = d_in[5];
    const void* btq  = d_in[6];
    const void* coup = d_in[7];
    const void* bwt  = d_in[8];

    float* UF   = (float*)d_ws;                                   // 8 MiB
    float* CFUC = (float*)((char*)d_ws + (size_t)BN * CN * SS * 4); // 1 MiB
    int*   flag = (int*)((char*)d_ws + (size_t)BN * CN * SS * 4
                                     + (size_t)BN * SS * 4);

    detect_kernel<<<1, 256, 0, stream>>>(u, flag);
    ka_kernel<<<BN * SN, 128, 0, stream>>>(u, ab, atc, atq, coup, bwt,
                                           UF, CFUC, 0.0f, flag);
    for (int k = 0; k < NSTEPS; ++k) {
        kb_kernel<<<BN * CN * (SN / 32), 256, 0, stream>>>(
            bb, btc, btq, bwt, UF, CFUC, ((float)k + 0.5f) * DTC, flag);
        kc_kernel<<<BN * SN, 128, 0, stream>>>(
            ab, atc, atq, coup, bwt, UF, CFUC, d_out,
            ((float)k + 1.0f) * DTC, (k == NSTEPS - 1) ? 1 : 0, flag);
    }
}